// Round 5
// baseline (87.566 us; speedup 1.0000x reference)
//
#include <hip/hip_runtime.h>
#include <cmath>

namespace {
constexpr int B_ = 2, K_ = 4, D_ = 128, L_ = 4096, N_ = 16, R_ = 8, C_ = 40;
constexpr float LOG2E = 1.44269504f;
}

#if __has_builtin(__builtin_amdgcn_exp2f)
#define FEXP2(x) __builtin_amdgcn_exp2f(x)
#else
#define FEXP2(x) exp2f(x)
#endif

// ---------------------------------------------------------------------------
// K1: projections. Grid 256 blocks (b,k,32 l-tiles of 128). Block = 640 thr =
// 10 waves; wave w computes 4 channels (w0-5 kv path: dts+B, w6-9 q path: C).
// Lane = (dg, lq): d-half x 32 float4 l-slots; halves via shfl_xor(32).
// ---------------------------------------------------------------------------
__global__ __launch_bounds__(640, 2) void k1_proj(
    const float* __restrict__ qx, const float* __restrict__ kv,
    const float* __restrict__ xw,   // (K, 40, D)
    float* __restrict__ dtsT,       // (B,K,L,8)
    float* __restrict__ BT,         // (B,K,L,16)
    float* __restrict__ CT)         // (B,K,L,16)
{
    __shared__ float Wt[D_ * C_];   // [d][c]

    const int tid = threadIdx.x;
    const int w = tid >> 6, lane = tid & 63;
    const int dg = lane >> 5, lq = lane & 31;
    int blk = blockIdx.x;
    const int lt = blk & 31; blk >>= 5;
    const int k = blk & 3; const int b = blk >> 2;
    const int bk = b * K_ + k;

    for (int i = tid; i < C_ * D_; i += 640) {
        const int c = i >> 7, d = i & 127;
        Wt[d * C_ + c] = xw[(k * C_ + c) * D_ + d];
    }
    __syncthreads();

    const float* xsrc = (w >= 6) ? qx : kv;
    const int c0 = w * 4;
    float acc[4][4];
    #pragma unroll
    for (int c = 0; c < 4; ++c)
        #pragma unroll
        for (int j = 0; j < 4; ++j) acc[c][j] = 0.f;

    const float* src = xsrc + ((size_t)bk * D_ + dg * 64) * L_ + lt * 128 + 4 * lq;
    #pragma unroll 8
    for (int dd = 0; dd < 64; ++dd) {
        const float4 x = *(const float4*)(src + (size_t)dd * L_);
        const float4 wv = *(const float4*)&Wt[(dg * 64 + dd) * C_ + c0];
        const float* wp = (const float*)&wv;
        #pragma unroll
        for (int c = 0; c < 4; ++c) {
            acc[c][0] = fmaf(x.x, wp[c], acc[c][0]);
            acc[c][1] = fmaf(x.y, wp[c], acc[c][1]);
            acc[c][2] = fmaf(x.z, wp[c], acc[c][2]);
            acc[c][3] = fmaf(x.w, wp[c], acc[c][3]);
        }
    }

    #pragma unroll
    for (int c = 0; c < 4; ++c)
        #pragma unroll
        for (int j = 0; j < 4; ++j)
            acc[c][j] += __shfl_xor(acc[c][j], 32, 64);

    if (dg == 0) {
        #pragma unroll
        for (int j = 0; j < 4; ++j) {
            const int l = lt * 128 + 4 * lq + j;
            float4 o; o.x = acc[0][j]; o.y = acc[1][j]; o.z = acc[2][j]; o.w = acc[3][j];
            if (w < 2)
                *(float4*)(dtsT + ((size_t)bk * L_ + l) * R_ + w * 4) = o;
            else if (w < 6)
                *(float4*)(BT + ((size_t)bk * L_ + l) * N_ + (w - 2) * 4) = o;
            else
                *(float4*)(CT + ((size_t)bk * L_ + l) * N_ + (w - 6) * 4) = o;
        }
    }
}

// ---------------------------------------------------------------------------
// K2: chunk pass 1. Thread = d (128/block), per (b,k,chunk). launch_bounds
// (128,1): VGPR<=256, no spill; occupancy LDS-bound (39.3KB -> 4 blocks/CU).
// n processed in 4 float4 groups to cut live temps.
// ---------------------------------------------------------------------------
template<int CHUNK>
__global__ __launch_bounds__(128, 1) void k2_pass1(
    const float* __restrict__ kv, const float* __restrict__ dtsT,
    const float* __restrict__ BT, const float* __restrict__ alg,
    const float* __restrict__ dtw, const float* __restrict__ dtb,
    float* __restrict__ hend, float* __restrict__ Ssum)
{
    constexpr int NCH = L_ / CHUNK;
    constexpr int S = CHUNK + 1;
    constexpr int J = CHUNK / 4;
    __shared__ float u_s[D_ * S];
    __shared__ float dts_s[CHUNK * R_];
    __shared__ float B_s[CHUNK * N_];

    const int tid = threadIdx.x;
    const int d = tid;
    int blk = blockIdx.x;
    const int ch = blk % NCH; blk /= NCH;
    const int k = blk % K_; const int b = blk / K_;
    const int bk = b * K_ + k;

    for (int f = tid; f < D_ * J; f += 128) {
        const int d0 = f / J, j4 = (f % J) * 4;
        float4 v = *(const float4*)(kv + ((size_t)bk * D_ + d0) * L_ + ch * CHUNK + j4);
        float* p = &u_s[d0 * S + j4];
        p[0] = v.x; p[1] = v.y; p[2] = v.z; p[3] = v.w;
    }
    {
        const float* src = dtsT + ((size_t)bk * L_ + ch * CHUNK) * R_;
        for (int f = tid; f < CHUNK * 2; f += 128)
            *(float4*)&dts_s[4 * f] = *(const float4*)(src + 4 * f);
        const float* bsrc = BT + ((size_t)bk * L_ + ch * CHUNK) * N_;
        for (int f = tid; f < CHUNK * 4; f += 128)
            *(float4*)&B_s[4 * f] = *(const float4*)(bsrc + 4 * f);
    }
    __syncthreads();

    float dtwr[R_];
    {
        const float* p = dtw + ((size_t)k * D_ + d) * R_;
        *(float4*)&dtwr[0] = *(const float4*)p;
        *(float4*)&dtwr[4] = *(const float4*)(p + 4);
    }
    const float bias = dtb[k * D_ + d];
    float A2[N_];
    {
        const float* ap = alg + ((size_t)k * D_ + d) * N_;
        #pragma unroll
        for (int j = 0; j < 4; ++j) {
            float4 a = *(const float4*)(ap + 4 * j);
            A2[4*j]   = -__expf(a.x) * LOG2E; A2[4*j+1] = -__expf(a.y) * LOG2E;
            A2[4*j+2] = -__expf(a.z) * LOG2E; A2[4*j+3] = -__expf(a.w) * LOG2E;
        }
    }

    float h[N_];
    #pragma unroll
    for (int n = 0; n < N_; ++n) h[n] = 0.f;
    float sd = 0.f;

    #pragma unroll 2
    for (int l = 0; l < CHUNK; ++l) {
        float dv[R_];
        *(float4*)&dv[0] = *(const float4*)&dts_s[l * R_];
        *(float4*)&dv[4] = *(const float4*)&dts_s[l * R_ + 4];
        float s = bias;
        #pragma unroll
        for (int r = 0; r < R_; ++r) s = fmaf(dv[r], dtwr[r], s);
        const float e = FEXP2(s * LOG2E);
        const float dlt = (s > 15.f) ? s : __logf(1.f + e);
        sd += dlt;
        const float xb = dlt * u_s[d * S + l];
        #pragma unroll
        for (int g = 0; g < 4; ++g) {
            const float4 bg = *(const float4*)&B_s[l * N_ + 4 * g];
            h[4*g+0] = fmaf(FEXP2(dlt * A2[4*g+0]), h[4*g+0], xb * bg.x);
            h[4*g+1] = fmaf(FEXP2(dlt * A2[4*g+1]), h[4*g+1], xb * bg.y);
            h[4*g+2] = fmaf(FEXP2(dlt * A2[4*g+2]), h[4*g+2], xb * bg.z);
            h[4*g+3] = fmaf(FEXP2(dlt * A2[4*g+3]), h[4*g+3], xb * bg.w);
        }
    }

    float* hp = hend + (((size_t)bk * NCH + ch) * D_ + d) * N_;
    #pragma unroll
    for (int j = 0; j < 4; ++j) {
        float4 o; o.x = h[4*j]; o.y = h[4*j+1]; o.z = h[4*j+2]; o.w = h[4*j+3];
        *(float4*)(hp + 4 * j) = o;
    }
    Ssum[((size_t)bk * NCH + ch) * D_ + d] = sd;
}

// ---------------------------------------------------------------------------
// K2.5: serial chunk chain, hend -> hinit (exclusive prefix), batched loads.
// ---------------------------------------------------------------------------
template<int NCH>
__global__ __launch_bounds__(64, 2) void k25_chain(
    const float* __restrict__ alg, const float* __restrict__ Ssum,
    const float* __restrict__ hend, float* __restrict__ hinit)
{
    const int tg = blockIdx.x * 64 + threadIdx.x;   // 16384 threads
    const int n = tg & 15;
    const int d = (tg >> 4) & 127;
    const int bk = tg >> 11;
    const int k = bk & 3;

    const float A2 = -__expf(alg[((size_t)k * D_ + d) * N_ + n]) * LOG2E;
    float h = 0.f;
    for (int c0 = 0; c0 < NCH; c0 += 32) {
        float he[32], ss[32];
        #pragma unroll
        for (int j = 0; j < 32; ++j) {
            const size_t si = ((size_t)bk * NCH + c0 + j) * D_ + d;
            he[j] = hend[si * N_ + n];
            ss[j] = Ssum[si];
        }
        #pragma unroll
        for (int j = 0; j < 32; ++j) {
            const size_t si = ((size_t)bk * NCH + c0 + j) * D_ + d;
            hinit[si * N_ + n] = h;
            h = fmaf(FEXP2(ss[j] * A2), h, he[j]);
        }
    }
}

// ---------------------------------------------------------------------------
// K3: chunk pass 2. No y_s: y(+u*Ds) overwrites the thread-private u_s row in
// place (each thread reads only its own row at step l before writing it).
// LDS 43.3KB -> 3 blocks/CU; launch_bounds(128,1) -> no VGPR spill.
// ---------------------------------------------------------------------------
template<int CHUNK>
__global__ __launch_bounds__(128, 1) void k3_pass2(
    const float* __restrict__ kv, const float* __restrict__ dtsT,
    const float* __restrict__ BT, const float* __restrict__ CT,
    const float* __restrict__ alg, const float* __restrict__ dtw,
    const float* __restrict__ dtb, const float* __restrict__ DsG,
    const float* __restrict__ hinit, float* __restrict__ out)
{
    constexpr int NCH = L_ / CHUNK;
    constexpr int S = CHUNK + 1;
    constexpr int J = CHUNK / 4;
    __shared__ float u_s[D_ * S];
    __shared__ float dts_s[CHUNK * R_];
    __shared__ float B_s[CHUNK * N_];
    __shared__ float C_s[CHUNK * N_];

    const int tid = threadIdx.x;
    const int d = tid;
    int blk = blockIdx.x;
    const int ch = blk % NCH; blk /= NCH;
    const int k = blk % K_; const int b = blk / K_;
    const int bk = b * K_ + k;

    for (int f = tid; f < D_ * J; f += 128) {
        const int d0 = f / J, j4 = (f % J) * 4;
        float4 v = *(const float4*)(kv + ((size_t)bk * D_ + d0) * L_ + ch * CHUNK + j4);
        float* p = &u_s[d0 * S + j4];
        p[0] = v.x; p[1] = v.y; p[2] = v.z; p[3] = v.w;
    }
    {
        const float* src = dtsT + ((size_t)bk * L_ + ch * CHUNK) * R_;
        for (int f = tid; f < CHUNK * 2; f += 128)
            *(float4*)&dts_s[4 * f] = *(const float4*)(src + 4 * f);
        const float* bsrc = BT + ((size_t)bk * L_ + ch * CHUNK) * N_;
        const float* csrc = CT + ((size_t)bk * L_ + ch * CHUNK) * N_;
        for (int f = tid; f < CHUNK * 4; f += 128) {
            *(float4*)&B_s[4 * f] = *(const float4*)(bsrc + 4 * f);
            *(float4*)&C_s[4 * f] = *(const float4*)(csrc + 4 * f);
        }
    }
    __syncthreads();

    float dtwr[R_];
    {
        const float* p = dtw + ((size_t)k * D_ + d) * R_;
        *(float4*)&dtwr[0] = *(const float4*)p;
        *(float4*)&dtwr[4] = *(const float4*)(p + 4);
    }
    const float bias = dtb[k * D_ + d];
    const float Dv = DsG[k * D_ + d];
    float A2[N_];
    {
        const float* ap = alg + ((size_t)k * D_ + d) * N_;
        #pragma unroll
        for (int j = 0; j < 4; ++j) {
            float4 a = *(const float4*)(ap + 4 * j);
            A2[4*j]   = -__expf(a.x) * LOG2E; A2[4*j+1] = -__expf(a.y) * LOG2E;
            A2[4*j+2] = -__expf(a.z) * LOG2E; A2[4*j+3] = -__expf(a.w) * LOG2E;
        }
    }

    float h[N_];
    {
        const float* hp = hinit + (((size_t)bk * NCH + ch) * D_ + d) * N_;
        #pragma unroll
        for (int j = 0; j < 4; ++j) {
            float4 v = *(const float4*)(hp + 4 * j);
            h[4*j] = v.x; h[4*j+1] = v.y; h[4*j+2] = v.z; h[4*j+3] = v.w;
        }
    }

    #pragma unroll 2
    for (int l = 0; l < CHUNK; ++l) {
        float dv[R_];
        *(float4*)&dv[0] = *(const float4*)&dts_s[l * R_];
        *(float4*)&dv[4] = *(const float4*)&dts_s[l * R_ + 4];
        float s = bias;
        #pragma unroll
        for (int r = 0; r < R_; ++r) s = fmaf(dv[r], dtwr[r], s);
        const float e = FEXP2(s * LOG2E);
        const float dlt = (s > 15.f) ? s : __logf(1.f + e);
        const float uu = u_s[d * S + l];
        const float xb = dlt * uu;
        float p0 = 0.f, p1 = 0.f;
        #pragma unroll
        for (int g = 0; g < 4; ++g) {
            const float4 bg = *(const float4*)&B_s[l * N_ + 4 * g];
            const float4 cg = *(const float4*)&C_s[l * N_ + 4 * g];
            h[4*g+0] = fmaf(FEXP2(dlt * A2[4*g+0]), h[4*g+0], xb * bg.x);
            p0 = fmaf(h[4*g+0], cg.x, p0);
            h[4*g+1] = fmaf(FEXP2(dlt * A2[4*g+1]), h[4*g+1], xb * bg.y);
            p1 = fmaf(h[4*g+1], cg.y, p1);
            h[4*g+2] = fmaf(FEXP2(dlt * A2[4*g+2]), h[4*g+2], xb * bg.z);
            p0 = fmaf(h[4*g+2], cg.z, p0);
            h[4*g+3] = fmaf(FEXP2(dlt * A2[4*g+3]), h[4*g+3], xb * bg.w);
            p1 = fmaf(h[4*g+3], cg.w, p1);
        }
        u_s[d * S + l] = fmaf(uu, Dv, p0 + p1);   // y + u*Ds, in place
    }
    __syncthreads();

    for (int f = tid; f < D_ * J; f += 128) {
        const int d0 = f / J, j4 = (f % J) * 4;
        const float* yp = &u_s[d0 * S + j4];
        float4 o; o.x = yp[0]; o.y = yp[1]; o.z = yp[2]; o.w = yp[3];
        *(float4*)(out + ((size_t)bk * D_ + d0) * L_ + ch * CHUNK + j4) = o;
    }
}

extern "C" void kernel_launch(void* const* d_in, const int* in_sizes, int n_in,
                              void* d_out, int out_size, void* d_ws, size_t ws_size,
                              hipStream_t stream)
{
    const float* qx  = (const float*)d_in[0];
    const float* kv  = (const float*)d_in[1];
    const float* xw  = (const float*)d_in[2];
    const float* dtw = (const float*)d_in[3];
    const float* dtb = (const float*)d_in[4];
    const float* alg = (const float*)d_in[5];
    const float* Ds  = (const float*)d_in[6];
    float* out = (float*)d_out;

    const size_t sz_dts = (size_t)B_ * K_ * L_ * R_;   // 262,144
    const size_t sz_bc  = (size_t)B_ * K_ * L_ * N_;   // 524,288

    auto need = [&](int NCH) {
        return (sz_dts + 2 * sz_bc
                + 2 * (size_t)B_ * K_ * NCH * D_ * N_
                + (size_t)B_ * K_ * NCH * D_) * sizeof(float);
    };

    float* dts = (float*)d_ws;
    float* BTp = dts + sz_dts;
    float* CTp = BTp + sz_bc;
    float* hend = CTp + sz_bc;

    k1_proj<<<B_ * K_ * 32, 640, 0, stream>>>(qx, kv, xw, dts, BTp, CTp);

    if (ws_size >= need(64)) {
        constexpr int CHUNK = 64, NCH = 64;
        const size_t sz_h = (size_t)B_ * K_ * NCH * D_ * N_;
        float* hinit = hend + sz_h;
        float* Ssm = hinit + sz_h;
        k2_pass1<CHUNK><<<B_ * K_ * NCH, 128, 0, stream>>>(kv, dts, BTp, alg, dtw, dtb, hend, Ssm);
        k25_chain<NCH><<<256, 64, 0, stream>>>(alg, Ssm, hend, hinit);
        k3_pass2<CHUNK><<<B_ * K_ * NCH, 128, 0, stream>>>(kv, dts, BTp, CTp, alg, dtw, dtb, Ds, hinit, out);
    } else if (ws_size >= need(32)) {
        constexpr int CHUNK = 128, NCH = 32;
        const size_t sz_h = (size_t)B_ * K_ * NCH * D_ * N_;
        float* hinit = hend + sz_h;
        float* Ssm = hinit + sz_h;
        k2_pass1<CHUNK><<<B_ * K_ * NCH, 128, 0, stream>>>(kv, dts, BTp, alg, dtw, dtb, hend, Ssm);
        k25_chain<NCH><<<256, 64, 0, stream>>>(alg, Ssm, hend, hinit);
        k3_pass2<CHUNK><<<B_ * K_ * NCH, 128, 0, stream>>>(kv, dts, BTp, CTp, alg, dtw, dtb, Ds, hinit, out);
    }
}

// Round 6
// 71.632 us; speedup vs baseline: 1.2224x; 1.2224x over previous
//
#include <hip/hip_runtime.h>
#include <cmath>

namespace {
constexpr int B_ = 2, K_ = 4, D_ = 128, L_ = 4096, N_ = 16, R_ = 8, C_ = 40;
constexpr int CHUNK = 32, NCH = L_ / CHUNK;   // 128 chunks of 32
constexpr float LOG2E = 1.44269504f;
}

#if __has_builtin(__builtin_amdgcn_exp2f)
#define FEXP2(x) __builtin_amdgcn_exp2f(x)
#else
#define FEXP2(x) exp2f(x)
#endif

// ---------------------------------------------------------------------------
// K0: kv (B,K,D,L) -> uT (B,K,L,D). 64x64 tiles via LDS, both sides coalesced.
// ---------------------------------------------------------------------------
__global__ __launch_bounds__(256, 4) void k0_transpose(
    const float* __restrict__ kv, float* __restrict__ uT)
{
    __shared__ float t[64 * 68];   // [dd][ll], stride 68 (16B-aligned rows)
    const int tid = threadIdx.x;
    int blk = blockIdx.x;
    const int lt = blk & 63; blk >>= 6;
    const int dt = blk & 1;  blk >>= 1;
    const int bk = blk;                      // 0..7
    const int d0 = dt * 64, l0 = lt * 64;

    #pragma unroll
    for (int p = 0; p < 4; ++p) {
        const int f = tid + p * 256;
        const int row = f >> 4, c4 = (f & 15) * 4;
        *(float4*)&t[row * 68 + c4] =
            *(const float4*)(kv + ((size_t)bk * D_ + d0 + row) * L_ + l0 + c4);
    }
    __syncthreads();
    #pragma unroll
    for (int p = 0; p < 4; ++p) {
        const int f = tid + p * 256;
        const int row = f >> 4, c4 = (f & 15) * 4;   // row = l-index, c4 = d-index
        float4 o;
        o.x = t[(c4 + 0) * 68 + row];
        o.y = t[(c4 + 1) * 68 + row];
        o.z = t[(c4 + 2) * 68 + row];
        o.w = t[(c4 + 3) * 68 + row];
        *(float4*)(uT + ((size_t)bk * L_ + l0 + row) * D_ + d0 + c4) = o;
    }
}

// ---------------------------------------------------------------------------
// K1: projections (unchanged from round 5). 256 blocks x 640 thr (10 waves);
// wave w computes 4 channels (w0-5 kv path: dts+B, w6-9 q path: C).
// ---------------------------------------------------------------------------
__global__ __launch_bounds__(640, 2) void k1_proj(
    const float* __restrict__ qx, const float* __restrict__ kv,
    const float* __restrict__ xw,   // (K, 40, D)
    float* __restrict__ dtsT,       // (B,K,L,8)
    float* __restrict__ BT,         // (B,K,L,16)
    float* __restrict__ CT)         // (B,K,L,16)
{
    __shared__ float Wt[D_ * C_];   // [d][c]

    const int tid = threadIdx.x;
    const int w = tid >> 6, lane = tid & 63;
    const int dg = lane >> 5, lq = lane & 31;
    int blk = blockIdx.x;
    const int lt = blk & 31; blk >>= 5;
    const int k = blk & 3; const int b = blk >> 2;
    const int bk = b * K_ + k;

    for (int i = tid; i < C_ * D_; i += 640) {
        const int c = i >> 7, d = i & 127;
        Wt[d * C_ + c] = xw[(k * C_ + c) * D_ + d];
    }
    __syncthreads();

    const float* xsrc = (w >= 6) ? qx : kv;
    const int c0 = w * 4;
    float acc[4][4];
    #pragma unroll
    for (int c = 0; c < 4; ++c)
        #pragma unroll
        for (int j = 0; j < 4; ++j) acc[c][j] = 0.f;

    const float* src = xsrc + ((size_t)bk * D_ + dg * 64) * L_ + lt * 128 + 4 * lq;
    #pragma unroll 8
    for (int dd = 0; dd < 64; ++dd) {
        const float4 x = *(const float4*)(src + (size_t)dd * L_);
        const float4 wv = *(const float4*)&Wt[(dg * 64 + dd) * C_ + c0];
        const float* wp = (const float*)&wv;
        #pragma unroll
        for (int c = 0; c < 4; ++c) {
            acc[c][0] = fmaf(x.x, wp[c], acc[c][0]);
            acc[c][1] = fmaf(x.y, wp[c], acc[c][1]);
            acc[c][2] = fmaf(x.z, wp[c], acc[c][2]);
            acc[c][3] = fmaf(x.w, wp[c], acc[c][3]);
        }
    }

    #pragma unroll
    for (int c = 0; c < 4; ++c)
        #pragma unroll
        for (int j = 0; j < 4; ++j)
            acc[c][j] += __shfl_xor(acc[c][j], 32, 64);

    if (dg == 0) {
        #pragma unroll
        for (int j = 0; j < 4; ++j) {
            const int l = lt * 128 + 4 * lq + j;
            float4 o; o.x = acc[0][j]; o.y = acc[1][j]; o.z = acc[2][j]; o.w = acc[3][j];
            if (w < 2)
                *(float4*)(dtsT + ((size_t)bk * L_ + l) * R_ + w * 4) = o;
            else if (w < 6)
                *(float4*)(BT + ((size_t)bk * L_ + l) * N_ + (w - 2) * 4) = o;
            else
                *(float4*)(CT + ((size_t)bk * L_ + l) * N_ + (w - 6) * 4) = o;
        }
    }
}

// ---------------------------------------------------------------------------
// K2: chunk pass 1. Thread = d, block = 128 thr, grid = B*K*NCH = 1024.
// u preloaded into 32 registers from l-major uT (coalesced); LDS only for
// broadcast dts/B (3 KB). Fully unrolled 32-step scan, 16 n-states in regs.
// ---------------------------------------------------------------------------
__global__ __launch_bounds__(128, 1) void k2_pass1(
    const float* __restrict__ uT, const float* __restrict__ dtsT,
    const float* __restrict__ BT, const float* __restrict__ alg,
    const float* __restrict__ dtw, const float* __restrict__ dtb,
    float* __restrict__ hend, float* __restrict__ Ssum)
{
    __shared__ float dts_s[CHUNK * R_];   // 1 KB
    __shared__ float B_s[CHUNK * N_];     // 2 KB

    const int tid = threadIdx.x;
    const int d = tid;
    const int blk = blockIdx.x;
    const int ch = blk & (NCH - 1);
    const int bk = blk >> 7;
    const int k = bk & 3;

    {
        const float* src = dtsT + ((size_t)bk * L_ + ch * CHUNK) * R_;
        if (tid < 64) *(float4*)&dts_s[4 * tid] = *(const float4*)(src + 4 * tid);
        const float* bsrc = BT + ((size_t)bk * L_ + ch * CHUNK) * N_;
        *(float4*)&B_s[4 * tid] = *(const float4*)(bsrc + 4 * tid);
    }

    // preload u chunk into registers (coalesced, independent loads)
    float uu[CHUNK];
    {
        const float* urow = uT + ((size_t)bk * L_ + ch * CHUNK) * D_ + d;
        #pragma unroll
        for (int l = 0; l < CHUNK; ++l) uu[l] = urow[(size_t)l * D_];
    }

    float dtwr[R_];
    {
        const float* p = dtw + ((size_t)k * D_ + d) * R_;
        *(float4*)&dtwr[0] = *(const float4*)p;
        *(float4*)&dtwr[4] = *(const float4*)(p + 4);
    }
    const float bias = dtb[k * D_ + d];
    float A2[N_];
    {
        const float* ap = alg + ((size_t)k * D_ + d) * N_;
        #pragma unroll
        for (int j = 0; j < 4; ++j) {
            float4 a = *(const float4*)(ap + 4 * j);
            A2[4*j]   = -__expf(a.x) * LOG2E; A2[4*j+1] = -__expf(a.y) * LOG2E;
            A2[4*j+2] = -__expf(a.z) * LOG2E; A2[4*j+3] = -__expf(a.w) * LOG2E;
        }
    }
    __syncthreads();

    float h[N_];
    #pragma unroll
    for (int n = 0; n < N_; ++n) h[n] = 0.f;
    float sd = 0.f;

    #pragma unroll
    for (int l = 0; l < CHUNK; ++l) {
        float dv[R_];
        *(float4*)&dv[0] = *(const float4*)&dts_s[l * R_];
        *(float4*)&dv[4] = *(const float4*)&dts_s[l * R_ + 4];
        float s = bias;
        #pragma unroll
        for (int r = 0; r < R_; ++r) s = fmaf(dv[r], dtwr[r], s);
        const float e = FEXP2(s * LOG2E);
        const float dlt = (s > 15.f) ? s : __logf(1.f + e);
        sd += dlt;
        const float xb = dlt * uu[l];
        #pragma unroll
        for (int g = 0; g < 4; ++g) {
            const float4 bg = *(const float4*)&B_s[l * N_ + 4 * g];
            h[4*g+0] = fmaf(FEXP2(dlt * A2[4*g+0]), h[4*g+0], xb * bg.x);
            h[4*g+1] = fmaf(FEXP2(dlt * A2[4*g+1]), h[4*g+1], xb * bg.y);
            h[4*g+2] = fmaf(FEXP2(dlt * A2[4*g+2]), h[4*g+2], xb * bg.z);
            h[4*g+3] = fmaf(FEXP2(dlt * A2[4*g+3]), h[4*g+3], xb * bg.w);
        }
    }

    float* hp = hend + (((size_t)bk * NCH + ch) * D_ + d) * N_;
    #pragma unroll
    for (int j = 0; j < 4; ++j) {
        float4 o; o.x = h[4*j]; o.y = h[4*j+1]; o.z = h[4*j+2]; o.w = h[4*j+3];
        *(float4*)(hp + 4 * j) = o;
    }
    Ssum[((size_t)bk * NCH + ch) * D_ + d] = sd;
}

// ---------------------------------------------------------------------------
// K2.5: serial chunk chain, hend -> hinit (exclusive prefix), 32-deep batched
// coalesced loads; exp off the dependence chain.
// ---------------------------------------------------------------------------
__global__ __launch_bounds__(64, 2) void k25_chain(
    const float* __restrict__ alg, const float* __restrict__ Ssum,
    const float* __restrict__ hend, float* __restrict__ hinit)
{
    const int tg = blockIdx.x * 64 + threadIdx.x;   // 16384 threads
    const int n = tg & 15;
    const int d = (tg >> 4) & 127;
    const int bk = tg >> 11;
    const int k = bk & 3;

    const float A2 = -__expf(alg[((size_t)k * D_ + d) * N_ + n]) * LOG2E;
    float h = 0.f;
    for (int c0 = 0; c0 < NCH; c0 += 32) {
        float he[32], ss[32];
        #pragma unroll
        for (int j = 0; j < 32; ++j) {
            const size_t si = ((size_t)bk * NCH + c0 + j) * D_ + d;
            he[j] = hend[si * N_ + n];
            ss[j] = Ssum[si];
        }
        #pragma unroll
        for (int j = 0; j < 32; ++j) {
            const size_t si = ((size_t)bk * NCH + c0 + j) * D_ + d;
            hinit[si * N_ + n] = h;
            h = fmaf(FEXP2(ss[j] * A2), h, he[j]);
        }
    }
}

// ---------------------------------------------------------------------------
// K3: chunk pass 2. u from registers (uT), y(+u*Ds) staged per-step into a
// conflict-free stride-33 LDS transpose tile, flushed coalesced d-major.
// LDS = 1+2+2+16.9 ~ 22.9 KB.
// ---------------------------------------------------------------------------
__global__ __launch_bounds__(128, 1) void k3_pass2(
    const float* __restrict__ uT, const float* __restrict__ dtsT,
    const float* __restrict__ BT, const float* __restrict__ CT,
    const float* __restrict__ alg, const float* __restrict__ dtw,
    const float* __restrict__ dtb, const float* __restrict__ DsG,
    const float* __restrict__ hinit, float* __restrict__ out)
{
    constexpr int YS = CHUNK + 1;         // 33: (d + l) bank spread, 2-way free
    __shared__ float dts_s[CHUNK * R_];
    __shared__ float B_s[CHUNK * N_];
    __shared__ float C_s[CHUNK * N_];
    __shared__ float y_s[D_ * YS];

    const int tid = threadIdx.x;
    const int d = tid;
    const int blk = blockIdx.x;
    const int ch = blk & (NCH - 1);
    const int bk = blk >> 7;
    const int k = bk & 3;

    {
        const float* src = dtsT + ((size_t)bk * L_ + ch * CHUNK) * R_;
        if (tid < 64) *(float4*)&dts_s[4 * tid] = *(const float4*)(src + 4 * tid);
        const float* bsrc = BT + ((size_t)bk * L_ + ch * CHUNK) * N_;
        *(float4*)&B_s[4 * tid] = *(const float4*)(bsrc + 4 * tid);
        const float* csrc = CT + ((size_t)bk * L_ + ch * CHUNK) * N_;
        *(float4*)&C_s[4 * tid] = *(const float4*)(csrc + 4 * tid);
    }

    float uu[CHUNK];
    {
        const float* urow = uT + ((size_t)bk * L_ + ch * CHUNK) * D_ + d;
        #pragma unroll
        for (int l = 0; l < CHUNK; ++l) uu[l] = urow[(size_t)l * D_];
    }

    float dtwr[R_];
    {
        const float* p = dtw + ((size_t)k * D_ + d) * R_;
        *(float4*)&dtwr[0] = *(const float4*)p;
        *(float4*)&dtwr[4] = *(const float4*)(p + 4);
    }
    const float bias = dtb[k * D_ + d];
    const float Dv = DsG[k * D_ + d];
    float A2[N_];
    {
        const float* ap = alg + ((size_t)k * D_ + d) * N_;
        #pragma unroll
        for (int j = 0; j < 4; ++j) {
            float4 a = *(const float4*)(ap + 4 * j);
            A2[4*j]   = -__expf(a.x) * LOG2E; A2[4*j+1] = -__expf(a.y) * LOG2E;
            A2[4*j+2] = -__expf(a.z) * LOG2E; A2[4*j+3] = -__expf(a.w) * LOG2E;
        }
    }

    float h[N_];
    {
        const float* hp = hinit + (((size_t)bk * NCH + ch) * D_ + d) * N_;
        #pragma unroll
        for (int j = 0; j < 4; ++j) {
            float4 v = *(const float4*)(hp + 4 * j);
            h[4*j] = v.x; h[4*j+1] = v.y; h[4*j+2] = v.z; h[4*j+3] = v.w;
        }
    }
    __syncthreads();

    #pragma unroll
    for (int l = 0; l < CHUNK; ++l) {
        float dv[R_];
        *(float4*)&dv[0] = *(const float4*)&dts_s[l * R_];
        *(float4*)&dv[4] = *(const float4*)&dts_s[l * R_ + 4];
        float s = bias;
        #pragma unroll
        for (int r = 0; r < R_; ++r) s = fmaf(dv[r], dtwr[r], s);
        const float e = FEXP2(s * LOG2E);
        const float dlt = (s > 15.f) ? s : __logf(1.f + e);
        const float xb = dlt * uu[l];
        float p0 = 0.f, p1 = 0.f;
        #pragma unroll
        for (int g = 0; g < 4; ++g) {
            const float4 bg = *(const float4*)&B_s[l * N_ + 4 * g];
            const float4 cg = *(const float4*)&C_s[l * N_ + 4 * g];
            h[4*g+0] = fmaf(FEXP2(dlt * A2[4*g+0]), h[4*g+0], xb * bg.x);
            p0 = fmaf(h[4*g+0], cg.x, p0);
            h[4*g+1] = fmaf(FEXP2(dlt * A2[4*g+1]), h[4*g+1], xb * bg.y);
            p1 = fmaf(h[4*g+1], cg.y, p1);
            h[4*g+2] = fmaf(FEXP2(dlt * A2[4*g+2]), h[4*g+2], xb * bg.z);
            p0 = fmaf(h[4*g+2], cg.z, p0);
            h[4*g+3] = fmaf(FEXP2(dlt * A2[4*g+3]), h[4*g+3], xb * bg.w);
            p1 = fmaf(h[4*g+3], cg.w, p1);
        }
        y_s[d * YS + l] = fmaf(uu[l], Dv, p0 + p1);   // y + u*Ds
    }
    __syncthreads();

    // flush d-major coalesced: 128 rows x 8 float4
    #pragma unroll
    for (int p = 0; p < 8; ++p) {
        const int f = tid + p * 128;
        const int row = f >> 3, j4 = (f & 7) * 4;
        const float* yp = &y_s[row * YS + j4];
        float4 o; o.x = yp[0]; o.y = yp[1]; o.z = yp[2]; o.w = yp[3];
        *(float4*)(out + ((size_t)bk * D_ + row) * L_ + ch * CHUNK + j4) = o;
    }
}

extern "C" void kernel_launch(void* const* d_in, const int* in_sizes, int n_in,
                              void* d_out, int out_size, void* d_ws, size_t ws_size,
                              hipStream_t stream)
{
    const float* qx  = (const float*)d_in[0];
    const float* kv  = (const float*)d_in[1];
    const float* xw  = (const float*)d_in[2];
    const float* dtw = (const float*)d_in[3];
    const float* dtb = (const float*)d_in[4];
    const float* alg = (const float*)d_in[5];
    const float* Ds  = (const float*)d_in[6];
    float* out = (float*)d_out;

    const size_t sz_dts = (size_t)B_ * K_ * L_ * R_;        //   262,144
    const size_t sz_bc  = (size_t)B_ * K_ * L_ * N_;        //   524,288
    const size_t sz_uT  = (size_t)B_ * K_ * L_ * D_;        // 4,194,304
    const size_t sz_h   = (size_t)B_ * K_ * NCH * D_ * N_;  // 2,097,152
    const size_t sz_ss  = (size_t)B_ * K_ * NCH * D_;       //   131,072
    const size_t need = (sz_dts + 2 * sz_bc + sz_uT + 2 * sz_h + sz_ss) * sizeof(float);
    if (ws_size < need) return;   // ~39 MB (ws is ~268 MB per fill evidence)

    float* dts   = (float*)d_ws;
    float* BTp   = dts + sz_dts;
    float* CTp   = BTp + sz_bc;
    float* uT    = CTp + sz_bc;
    float* hend  = uT + sz_uT;
    float* hinit = hend + sz_h;
    float* Ssm   = hinit + sz_h;

    k0_transpose<<<B_ * K_ * 2 * 64, 256, 0, stream>>>(kv, uT);
    k1_proj<<<B_ * K_ * 32, 640, 0, stream>>>(qx, kv, xw, dts, BTp, CTp);
    k2_pass1<<<B_ * K_ * NCH, 128, 0, stream>>>(uT, dts, BTp, alg, dtw, dtb, hend, Ssm);
    k25_chain<<<256, 64, 0, stream>>>(alg, Ssm, hend, hinit);
    k3_pass2<<<B_ * K_ * NCH, 128, 0, stream>>>(uT, dts, BTp, CTp, alg, dtw, dtb, Ds, hinit, out);
}

// Round 7
// 63.738 us; speedup vs baseline: 1.3738x; 1.1239x over previous
//
#include <hip/hip_runtime.h>
#include <cmath>

namespace {
constexpr int B_ = 2, K_ = 4, D_ = 128, L_ = 4096, N_ = 16, R_ = 8, C_ = 40;
constexpr int CHUNK = 32, NCH = L_ / CHUNK;   // 128 chunks of 32
constexpr float LOG2E = 1.44269504f;
}

#if __has_builtin(__builtin_amdgcn_exp2f)
#define FEXP2(x) __builtin_amdgcn_exp2f(x)
#else
#define FEXP2(x) exp2f(x)
#endif

// ---------------------------------------------------------------------------
// K1: projections. 256 blocks x 640 thr (10 waves); wave w computes 4
// channels (w0-5 kv path: dts+B, w6-9 q path: C). Lane = (dg, lq).
// ---------------------------------------------------------------------------
__global__ __launch_bounds__(640, 2) void k1_proj(
    const float* __restrict__ qx, const float* __restrict__ kv,
    const float* __restrict__ xw,   // (K, 40, D)
    float* __restrict__ dtsT,       // (B,K,L,8)
    float* __restrict__ BT,         // (B,K,L,16)
    float* __restrict__ CT)         // (B,K,L,16)
{
    __shared__ float Wt[D_ * C_];   // [d][c]

    const int tid = threadIdx.x;
    const int w = tid >> 6, lane = tid & 63;
    const int dg = lane >> 5, lq = lane & 31;
    int blk = blockIdx.x;
    const int lt = blk & 31; blk >>= 5;
    const int k = blk & 3; const int b = blk >> 2;
    const int bk = b * K_ + k;

    for (int i = tid; i < C_ * D_; i += 640) {
        const int c = i >> 7, d = i & 127;
        Wt[d * C_ + c] = xw[(k * C_ + c) * D_ + d];
    }
    __syncthreads();

    const float* xsrc = (w >= 6) ? qx : kv;
    const int c0 = w * 4;
    float acc[4][4];
    #pragma unroll
    for (int c = 0; c < 4; ++c)
        #pragma unroll
        for (int j = 0; j < 4; ++j) acc[c][j] = 0.f;

    const float* src = xsrc + ((size_t)bk * D_ + dg * 64) * L_ + lt * 128 + 4 * lq;
    #pragma unroll 8
    for (int dd = 0; dd < 64; ++dd) {
        const float4 x = *(const float4*)(src + (size_t)dd * L_);
        const float4 wv = *(const float4*)&Wt[(dg * 64 + dd) * C_ + c0];
        const float* wp = (const float*)&wv;
        #pragma unroll
        for (int c = 0; c < 4; ++c) {
            acc[c][0] = fmaf(x.x, wp[c], acc[c][0]);
            acc[c][1] = fmaf(x.y, wp[c], acc[c][1]);
            acc[c][2] = fmaf(x.z, wp[c], acc[c][2]);
            acc[c][3] = fmaf(x.w, wp[c], acc[c][3]);
        }
    }

    #pragma unroll
    for (int c = 0; c < 4; ++c)
        #pragma unroll
        for (int j = 0; j < 4; ++j)
            acc[c][j] += __shfl_xor(acc[c][j], 32, 64);

    if (dg == 0) {
        #pragma unroll
        for (int j = 0; j < 4; ++j) {
            const int l = lt * 128 + 4 * lq + j;
            float4 o; o.x = acc[0][j]; o.y = acc[1][j]; o.z = acc[2][j]; o.w = acc[3][j];
            if (w < 2)
                *(float4*)(dtsT + ((size_t)bk * L_ + l) * R_ + w * 4) = o;
            else if (w < 6)
                *(float4*)(BT + ((size_t)bk * L_ + l) * N_ + (w - 2) * 4) = o;
            else
                *(float4*)(CT + ((size_t)bk * L_ + l) * N_ + (w - 6) * 4) = o;
        }
    }
}

// ---------------------------------------------------------------------------
// K2: chunk pass 1. Thread = d, block = 128 thr, grid = B*K*NCH = 1024.
// u loaded DIRECTLY from kv: thread d's chunk is 128 contiguous bytes
// (8x float4) - no transpose pass needed. LDS only for broadcast dts/B.
// ---------------------------------------------------------------------------
__global__ __launch_bounds__(128, 1) void k2_pass1(
    const float* __restrict__ kv, const float* __restrict__ dtsT,
    const float* __restrict__ BT, const float* __restrict__ alg,
    const float* __restrict__ dtw, const float* __restrict__ dtb,
    float* __restrict__ hend, float* __restrict__ Ssum)
{
    __shared__ float dts_s[CHUNK * R_];   // 1 KB
    __shared__ float B_s[CHUNK * N_];     // 2 KB

    const int tid = threadIdx.x;
    const int d = tid;
    const int blk = blockIdx.x;
    const int ch = blk & (NCH - 1);
    const int bk = blk >> 7;
    const int k = bk & 3;

    {
        const float* src = dtsT + ((size_t)bk * L_ + ch * CHUNK) * R_;
        if (tid < 64) *(float4*)&dts_s[4 * tid] = *(const float4*)(src + 4 * tid);
        const float* bsrc = BT + ((size_t)bk * L_ + ch * CHUNK) * N_;
        *(float4*)&B_s[4 * tid] = *(const float4*)(bsrc + 4 * tid);
    }

    // u chunk: 32 consecutive floats of kv row d -> 8 contiguous float4 loads
    float uu[CHUNK];
    {
        const float4* up = (const float4*)(kv + ((size_t)bk * D_ + d) * L_ + ch * CHUNK);
        #pragma unroll
        for (int j = 0; j < 8; ++j) {
            const float4 v = up[j];
            uu[4*j] = v.x; uu[4*j+1] = v.y; uu[4*j+2] = v.z; uu[4*j+3] = v.w;
        }
    }

    float dtwr[R_];
    {
        const float* p = dtw + ((size_t)k * D_ + d) * R_;
        *(float4*)&dtwr[0] = *(const float4*)p;
        *(float4*)&dtwr[4] = *(const float4*)(p + 4);
    }
    const float bias = dtb[k * D_ + d];
    float A2[N_];
    {
        const float* ap = alg + ((size_t)k * D_ + d) * N_;
        #pragma unroll
        for (int j = 0; j < 4; ++j) {
            float4 a = *(const float4*)(ap + 4 * j);
            A2[4*j]   = -__expf(a.x) * LOG2E; A2[4*j+1] = -__expf(a.y) * LOG2E;
            A2[4*j+2] = -__expf(a.z) * LOG2E; A2[4*j+3] = -__expf(a.w) * LOG2E;
        }
    }
    __syncthreads();

    float h[N_];
    #pragma unroll
    for (int n = 0; n < N_; ++n) h[n] = 0.f;
    float sd = 0.f;

    #pragma unroll
    for (int l = 0; l < CHUNK; ++l) {
        float dv[R_];
        *(float4*)&dv[0] = *(const float4*)&dts_s[l * R_];
        *(float4*)&dv[4] = *(const float4*)&dts_s[l * R_ + 4];
        float s = bias;
        #pragma unroll
        for (int r = 0; r < R_; ++r) s = fmaf(dv[r], dtwr[r], s);
        const float e = FEXP2(s * LOG2E);
        const float dlt = (s > 15.f) ? s : __logf(1.f + e);
        sd += dlt;
        const float xb = dlt * uu[l];
        #pragma unroll
        for (int g = 0; g < 4; ++g) {
            const float4 bg = *(const float4*)&B_s[l * N_ + 4 * g];
            h[4*g+0] = fmaf(FEXP2(dlt * A2[4*g+0]), h[4*g+0], xb * bg.x);
            h[4*g+1] = fmaf(FEXP2(dlt * A2[4*g+1]), h[4*g+1], xb * bg.y);
            h[4*g+2] = fmaf(FEXP2(dlt * A2[4*g+2]), h[4*g+2], xb * bg.z);
            h[4*g+3] = fmaf(FEXP2(dlt * A2[4*g+3]), h[4*g+3], xb * bg.w);
        }
    }

    float* hp = hend + (((size_t)bk * NCH + ch) * D_ + d) * N_;
    #pragma unroll
    for (int j = 0; j < 4; ++j) {
        float4 o; o.x = h[4*j]; o.y = h[4*j+1]; o.z = h[4*j+2]; o.w = h[4*j+3];
        *(float4*)(hp + 4 * j) = o;
    }
    Ssum[((size_t)bk * NCH + ch) * D_ + d] = sd;
}

// ---------------------------------------------------------------------------
// K2.5: serial chunk chain, hend -> hinit (exclusive prefix), 32-deep batched
// coalesced loads; exp off the dependence chain.
// ---------------------------------------------------------------------------
__global__ __launch_bounds__(64, 2) void k25_chain(
    const float* __restrict__ alg, const float* __restrict__ Ssum,
    const float* __restrict__ hend, float* __restrict__ hinit)
{
    const int tg = blockIdx.x * 64 + threadIdx.x;   // 16384 threads
    const int n = tg & 15;
    const int d = (tg >> 4) & 127;
    const int bk = tg >> 11;
    const int k = bk & 3;

    const float A2 = -__expf(alg[((size_t)k * D_ + d) * N_ + n]) * LOG2E;
    float h = 0.f;
    for (int c0 = 0; c0 < NCH; c0 += 32) {
        float he[32], ss[32];
        #pragma unroll
        for (int j = 0; j < 32; ++j) {
            const size_t si = ((size_t)bk * NCH + c0 + j) * D_ + d;
            he[j] = hend[si * N_ + n];
            ss[j] = Ssum[si];
        }
        #pragma unroll
        for (int j = 0; j < 32; ++j) {
            const size_t si = ((size_t)bk * NCH + c0 + j) * D_ + d;
            hinit[si * N_ + n] = h;
            h = fmaf(FEXP2(ss[j] * A2), h, he[j]);
        }
    }
}

// ---------------------------------------------------------------------------
// K3: chunk pass 2. u direct from kv (contiguous per-thread); y(+u*Ds) staged
// into stride-33 LDS transpose tile, flushed coalesced d-major.
// ---------------------------------------------------------------------------
__global__ __launch_bounds__(128, 1) void k3_pass2(
    const float* __restrict__ kv, const float* __restrict__ dtsT,
    const float* __restrict__ BT, const float* __restrict__ CT,
    const float* __restrict__ alg, const float* __restrict__ dtw,
    const float* __restrict__ dtb, const float* __restrict__ DsG,
    const float* __restrict__ hinit, float* __restrict__ out)
{
    constexpr int YS = CHUNK + 1;         // 33: bank spread, 2-way free
    __shared__ float dts_s[CHUNK * R_];
    __shared__ float B_s[CHUNK * N_];
    __shared__ float C_s[CHUNK * N_];
    __shared__ float y_s[D_ * YS];

    const int tid = threadIdx.x;
    const int d = tid;
    const int blk = blockIdx.x;
    const int ch = blk & (NCH - 1);
    const int bk = blk >> 7;
    const int k = bk & 3;

    {
        const float* src = dtsT + ((size_t)bk * L_ + ch * CHUNK) * R_;
        if (tid < 64) *(float4*)&dts_s[4 * tid] = *(const float4*)(src + 4 * tid);
        const float* bsrc = BT + ((size_t)bk * L_ + ch * CHUNK) * N_;
        *(float4*)&B_s[4 * tid] = *(const float4*)(bsrc + 4 * tid);
        const float* csrc = CT + ((size_t)bk * L_ + ch * CHUNK) * N_;
        *(float4*)&C_s[4 * tid] = *(const float4*)(csrc + 4 * tid);
    }

    float uu[CHUNK];
    {
        const float4* up = (const float4*)(kv + ((size_t)bk * D_ + d) * L_ + ch * CHUNK);
        #pragma unroll
        for (int j = 0; j < 8; ++j) {
            const float4 v = up[j];
            uu[4*j] = v.x; uu[4*j+1] = v.y; uu[4*j+2] = v.z; uu[4*j+3] = v.w;
        }
    }

    float dtwr[R_];
    {
        const float* p = dtw + ((size_t)k * D_ + d) * R_;
        *(float4*)&dtwr[0] = *(const float4*)p;
        *(float4*)&dtwr[4] = *(const float4*)(p + 4);
    }
    const float bias = dtb[k * D_ + d];
    const float Dv = DsG[k * D_ + d];
    float A2[N_];
    {
        const float* ap = alg + ((size_t)k * D_ + d) * N_;
        #pragma unroll
        for (int j = 0; j < 4; ++j) {
            float4 a = *(const float4*)(ap + 4 * j);
            A2[4*j]   = -__expf(a.x) * LOG2E; A2[4*j+1] = -__expf(a.y) * LOG2E;
            A2[4*j+2] = -__expf(a.z) * LOG2E; A2[4*j+3] = -__expf(a.w) * LOG2E;
        }
    }

    float h[N_];
    {
        const float* hp = hinit + (((size_t)bk * NCH + ch) * D_ + d) * N_;
        #pragma unroll
        for (int j = 0; j < 4; ++j) {
            float4 v = *(const float4*)(hp + 4 * j);
            h[4*j] = v.x; h[4*j+1] = v.y; h[4*j+2] = v.z; h[4*j+3] = v.w;
        }
    }
    __syncthreads();

    #pragma unroll
    for (int l = 0; l < CHUNK; ++l) {
        float dv[R_];
        *(float4*)&dv[0] = *(const float4*)&dts_s[l * R_];
        *(float4*)&dv[4] = *(const float4*)&dts_s[l * R_ + 4];
        float s = bias;
        #pragma unroll
        for (int r = 0; r < R_; ++r) s = fmaf(dv[r], dtwr[r], s);
        const float e = FEXP2(s * LOG2E);
        const float dlt = (s > 15.f) ? s : __logf(1.f + e);
        const float xb = dlt * uu[l];
        float p0 = 0.f, p1 = 0.f;
        #pragma unroll
        for (int g = 0; g < 4; ++g) {
            const float4 bg = *(const float4*)&B_s[l * N_ + 4 * g];
            const float4 cg = *(const float4*)&C_s[l * N_ + 4 * g];
            h[4*g+0] = fmaf(FEXP2(dlt * A2[4*g+0]), h[4*g+0], xb * bg.x);
            p0 = fmaf(h[4*g+0], cg.x, p0);
            h[4*g+1] = fmaf(FEXP2(dlt * A2[4*g+1]), h[4*g+1], xb * bg.y);
            p1 = fmaf(h[4*g+1], cg.y, p1);
            h[4*g+2] = fmaf(FEXP2(dlt * A2[4*g+2]), h[4*g+2], xb * bg.z);
            p0 = fmaf(h[4*g+2], cg.z, p0);
            h[4*g+3] = fmaf(FEXP2(dlt * A2[4*g+3]), h[4*g+3], xb * bg.w);
            p1 = fmaf(h[4*g+3], cg.w, p1);
        }
        y_s[d * YS + l] = fmaf(uu[l], Dv, p0 + p1);   // y + u*Ds
    }
    __syncthreads();

    // flush d-major coalesced: 128 rows x 8 float4
    #pragma unroll
    for (int p = 0; p < 8; ++p) {
        const int f = tid + p * 128;
        const int row = f >> 3, j4 = (f & 7) * 4;
        const float* yp = &y_s[row * YS + j4];
        float4 o; o.x = yp[0]; o.y = yp[1]; o.z = yp[2]; o.w = yp[3];
        *(float4*)(out + ((size_t)bk * D_ + row) * L_ + ch * CHUNK + j4) = o;
    }
}

extern "C" void kernel_launch(void* const* d_in, const int* in_sizes, int n_in,
                              void* d_out, int out_size, void* d_ws, size_t ws_size,
                              hipStream_t stream)
{
    const float* qx  = (const float*)d_in[0];
    const float* kv  = (const float*)d_in[1];
    const float* xw  = (const float*)d_in[2];
    const float* dtw = (const float*)d_in[3];
    const float* dtb = (const float*)d_in[4];
    const float* alg = (const float*)d_in[5];
    const float* Ds  = (const float*)d_in[6];
    float* out = (float*)d_out;

    const size_t sz_dts = (size_t)B_ * K_ * L_ * R_;        //   262,144
    const size_t sz_bc  = (size_t)B_ * K_ * L_ * N_;        //   524,288
    const size_t sz_h   = (size_t)B_ * K_ * NCH * D_ * N_;  // 2,097,152
    const size_t sz_ss  = (size_t)B_ * K_ * NCH * D_;       //   131,072
    const size_t need = (sz_dts + 2 * sz_bc + 2 * sz_h + sz_ss) * sizeof(float);
    if (ws_size < need) return;   // ~22.5 MB

    float* dts   = (float*)d_ws;
    float* BTp   = dts + sz_dts;
    float* CTp   = BTp + sz_bc;
    float* hend  = CTp + sz_bc;
    float* hinit = hend + sz_h;
    float* Ssm   = hinit + sz_h;

    k1_proj<<<B_ * K_ * 32, 640, 0, stream>>>(qx, kv, xw, dts, BTp, CTp);
    k2_pass1<<<B_ * K_ * NCH, 128, 0, stream>>>(kv, dts, BTp, alg, dtw, dtb, hend, Ssm);
    k25_chain<<<256, 64, 0, stream>>>(alg, Ssm, hend, hinit);
    k3_pass2<<<B_ * K_ * NCH, 128, 0, stream>>>(kv, dts, BTp, CTp, alg, dtw, dtb, Ds, hinit, out);
}